// Round 11
// baseline (345.211 us; speedup 1.0000x reference)
//
#include <hip/hip_runtime.h>
#include <hip/hip_bf16.h>

// Problem: B=256, T=256, C=384, H=64, MAX_REL=3 (causal -> rel idx 0..3 only)
// Round 18: ABLATION ROUND. r17 proved spill was real but not critical-path
// (WRITE 42.8->25.6 MB, dur unchanged 76 us). Six schedule/register theories
// failed; micro-models undershoot phase-1's measured 36 us. Ablate phase-1:
//   V0: full phase-1 x3 (anchor)            V1: ds_read+MFMA core x4 (no x)
//   V2: uncoalesced x-stream + cvt x5       V4: segment-optimal x-stream x5
// All 512thr + 150KB LDS (1 block/CU fidelity). Runtime nrep defeats
// unroll/CSE; acc/sink chains defeat DCE (g_diag consumer). fused = r17
// verbatim (passed, 76.2 us) for the real output.

typedef __attribute__((ext_vector_type(8))) __bf16 bf16x8;
typedef __attribute__((ext_vector_type(8))) short short8;
typedef __attribute__((ext_vector_type(4))) float f32x4;
typedef __attribute__((ext_vector_type(4))) int   i32x4;

#define MFMA16(A, B, C) __builtin_amdgcn_mfma_f32_16x16x32_bf16((A), (B), (C), 0, 0, 0)

__device__ __forceinline__ unsigned short f2bf(float f) {
    unsigned int u = __builtin_bit_cast(unsigned int, f);
    u = (u + 0x7FFFu + ((u >> 16) & 1u)) >> 16;   // RNE
    return (unsigned short)u;
}
__device__ __forceinline__ float bf2f(unsigned short s) {
    unsigned int u = ((unsigned int)s) << 16;
    return __builtin_bit_cast(float, u);
}
__device__ __forceinline__ bf16x8 ld16(const unsigned short* p) {
    return __builtin_bit_cast(bf16x8, *(const i32x4*)p);
}

__device__ float g_diag[256 * 1024];   // diag sink; never feeds out

// ---------------------------------------------------------------------------
__global__ void prep_wt(const float* __restrict__ Wq, const float* __restrict__ Wk,
                        const float* __restrict__ Wv, const float* __restrict__ relk,
                        unsigned short* __restrict__ Wt, unsigned short* __restrict__ Rk) {
    int i = blockIdx.x * 256 + threadIdx.x;
    if (i < 3 * 64 * 384) {
        int kk = i % 384;
        int h  = (i / 384) & 63;
        int w  = i / (384 * 64);
        const float* W = (w == 0) ? Wq : ((w == 1) ? Wk : Wv);
        Wt[i] = f2bf(W[kk * 64 + h]);
    } else if (i < 3 * 64 * 384 + 1024) {
        int j = i - 3 * 64 * 384;
        int n = j >> 6, h = j & 63;
        Rk[j] = (n < 4) ? f2bf(relk[n * 64 + h]) : (unsigned short)0;
    }
}

// ---------------------------------------------------------------------------
// V0: full phase-1 (x ring + cvt + ds_read + MFMA + LDS epilogue) x nrep
// ---------------------------------------------------------------------------
__global__ __launch_bounds__(512)
__attribute__((amdgpu_waves_per_eu(2, 2)))
void diag_v0(const float* __restrict__ x, const unsigned short* __restrict__ Wt, int nrep) {
    extern __shared__ unsigned short sh[];
    unsigned short* ws  = sh;
    unsigned short* ksh = sh;
    unsigned short* vTs = sh + 18432;
    unsigned short* qs  = sh + 35328;

    const int tid = threadIdx.x, wave = tid >> 6, lane = tid & 63;
    const int c = lane & 15, quad = lane >> 4, b = blockIdx.x;
    const f32x4 zero = {0.f, 0.f, 0.f, 0.f};
    const float* xc0 = x + (size_t)(b * 256 + wave * 32 + c) * 384 + quad * 8;
    const float* xc1 = xc0 + 16 * 384;

#pragma unroll
    for (int it = 0; it < 18; it++) {
        int P_ = it * 512 + tid;
        int r = P_ / 48, pc = P_ % 48;
        i32x4 d = *(const i32x4*)(Wt + r * 384 + pc * 8);
        *(i32x4*)(ws + r * 392 + pc * 8) = d;
    }
    __syncthreads();

    for (int rep = 0; rep < nrep; rep++) {     // runtime trip: no unroll/CSE
        f32x4 aq[2][4], ak[2][4], av[2][4];
#pragma unroll
        for (int rt = 0; rt < 2; rt++)
#pragma unroll
            for (int nt = 0; nt < 4; nt++) { aq[rt][nt] = zero; ak[rt][nt] = zero; av[rt][nt] = zero; }

        f32x4 t[3][2][2];
#pragma unroll
        for (int j = 0; j < 2; j++) {
            t[j][0][0] = *(const f32x4*)(xc0 + j * 32);
            t[j][0][1] = *(const f32x4*)(xc0 + j * 32 + 4);
            t[j][1][0] = *(const f32x4*)(xc1 + j * 32);
            t[j][1][1] = *(const f32x4*)(xc1 + j * 32 + 4);
        }
#pragma unroll
        for (int j = 0; j < 12; j++) {
            if (j < 10) {
                t[(j + 2) % 3][0][0] = *(const f32x4*)(xc0 + (j + 2) * 32);
                t[(j + 2) % 3][0][1] = *(const f32x4*)(xc0 + (j + 2) * 32 + 4);
                t[(j + 2) % 3][1][0] = *(const f32x4*)(xc1 + (j + 2) * 32);
                t[(j + 2) % 3][1][1] = *(const f32x4*)(xc1 + (j + 2) * 32 + 4);
            }
            bf16x8 a[2];
#pragma unroll
            for (int rt = 0; rt < 2; rt++) {
                short8 xs8;
#pragma unroll
                for (int e = 0; e < 4; e++) {
                    xs8[e]     = (short)f2bf(t[j % 3][rt][0][e]);
                    xs8[4 + e] = (short)f2bf(t[j % 3][rt][1][e]);
                }
                a[rt] = __builtin_bit_cast(bf16x8, xs8);
            }
            const int col = j * 32 + quad * 8;
#pragma unroll
            for (int nt = 0; nt < 4; nt++) {
                bf16x8 bq = ld16(ws + (nt * 16 + c) * 392 + col);
                bf16x8 bk = ld16(ws + (64 + nt * 16 + c) * 392 + col);
                bf16x8 aw = ld16(ws + (128 + nt * 16 + c) * 392 + col);
                aq[0][nt] = MFMA16(a[0], bq, aq[0][nt]);
                aq[1][nt] = MFMA16(a[1], bq, aq[1][nt]);
                ak[0][nt] = MFMA16(a[0], bk, ak[0][nt]);
                ak[1][nt] = MFMA16(a[1], bk, ak[1][nt]);
                av[0][nt] = MFMA16(aw, a[0], av[0][nt]);
                av[1][nt] = MFMA16(aw, a[1], av[1][nt]);
            }
        }
        __syncthreads();
#pragma unroll
        for (int rt = 0; rt < 2; rt++)
#pragma unroll
            for (int nt = 0; nt < 4; nt++)
#pragma unroll
                for (int r = 0; r < 4; r++) {
                    int row = wave * 32 + rt * 16 + quad * 4 + r;
                    qs[row * 72 + nt * 16 + c]  = f2bf(aq[rt][nt][r]);
                    ksh[row * 72 + nt * 16 + c] = f2bf(ak[rt][nt][r]);
                    vTs[(nt * 16 + quad * 4 + r) * 264 + wave * 32 + rt * 16 + c]
                        = f2bf(av[rt][nt][r]);
                }
        __syncthreads();
    }
    g_diag[b * 512 + tid] = bf2f(qs[tid]) + bf2f(ksh[tid + 7]) + bf2f(vTs[tid]);
}

// ---------------------------------------------------------------------------
// V1: ds_read + MFMA core only, x nrep (A-frags from relv, no x traffic)
// ---------------------------------------------------------------------------
__global__ __launch_bounds__(512)
__attribute__((amdgpu_waves_per_eu(2, 2)))
void diag_v1(const unsigned short* __restrict__ Wt, const float* __restrict__ relv, int nrep) {
    extern __shared__ unsigned short sh[];
    unsigned short* ws = sh;

    const int tid = threadIdx.x, lane = tid & 63;
    const int c = lane & 15, quad = lane >> 4, b = blockIdx.x;
    const f32x4 zero = {0.f, 0.f, 0.f, 0.f};

#pragma unroll
    for (int it = 0; it < 18; it++) {
        int P_ = it * 512 + tid;
        int r = P_ / 48, pc = P_ % 48;
        i32x4 d = *(const i32x4*)(Wt + r * 384 + pc * 8);
        *(i32x4*)(ws + r * 392 + pc * 8) = d;
    }
    __syncthreads();

    bf16x8 a[2];
#pragma unroll
    for (int rt = 0; rt < 2; rt++) {
        short8 s;
#pragma unroll
        for (int e = 0; e < 8; e++)
            s[e] = (short)f2bf(relv[(lane * 8 + e + rt * 160) & 255]);
        a[rt] = __builtin_bit_cast(bf16x8, s);
    }

    f32x4 aq[2][4], ak[2][4], av[2][4];
#pragma unroll
    for (int rt = 0; rt < 2; rt++)
#pragma unroll
        for (int nt = 0; nt < 4; nt++) { aq[rt][nt] = zero; ak[rt][nt] = zero; av[rt][nt] = zero; }

    for (int rep = 0; rep < nrep; rep++) {     // runtime trip
#pragma unroll
        for (int j = 0; j < 12; j++) {
            const int col = j * 32 + quad * 8;
#pragma unroll
            for (int nt = 0; nt < 4; nt++) {
                bf16x8 bq = ld16(ws + (nt * 16 + c) * 392 + col);
                bf16x8 bk = ld16(ws + (64 + nt * 16 + c) * 392 + col);
                bf16x8 aw = ld16(ws + (128 + nt * 16 + c) * 392 + col);
                aq[0][nt] = MFMA16(a[0], bq, aq[0][nt]);
                aq[1][nt] = MFMA16(a[1], bq, aq[1][nt]);
                ak[0][nt] = MFMA16(a[0], bk, ak[0][nt]);
                ak[1][nt] = MFMA16(a[1], bk, ak[1][nt]);
                av[0][nt] = MFMA16(aw, a[0], av[0][nt]);
                av[1][nt] = MFMA16(aw, a[1], av[1][nt]);
            }
        }
        __syncthreads();                       // keep waves phase-aligned per rep
    }
    float s = 0.f;
#pragma unroll
    for (int rt = 0; rt < 2; rt++)
#pragma unroll
        for (int nt = 0; nt < 4; nt++)
#pragma unroll
            for (int r = 0; r < 4; r++)
                s += aq[rt][nt][r] + ak[rt][nt][r] + av[rt][nt][r];
    g_diag[b * 512 + tid] = s;
}

// ---------------------------------------------------------------------------
// V2: UNCOALESCED x-stream + cvt only, x nrep (current phase-1 pattern)
// ---------------------------------------------------------------------------
__global__ __launch_bounds__(512)
__attribute__((amdgpu_waves_per_eu(2, 2)))
void diag_v2(const float* __restrict__ x, int nrep) {
    extern __shared__ unsigned short sh[];     // unused; forces 1 block/CU
    const int tid = threadIdx.x, wave = tid >> 6, lane = tid & 63;
    const int c = lane & 15, quad = lane >> 4, b = blockIdx.x;
    const float* xc0 = x + (size_t)(b * 256 + wave * 32 + c) * 384 + quad * 8;
    const float* xc1 = xc0 + 16 * 384;

    int sinki = 0;
    for (int rep = 0; rep < nrep; rep++) {     // runtime trip
        f32x4 t[3][2][2];
#pragma unroll
        for (int j = 0; j < 2; j++) {
            t[j][0][0] = *(const f32x4*)(xc0 + j * 32);
            t[j][0][1] = *(const f32x4*)(xc0 + j * 32 + 4);
            t[j][1][0] = *(const f32x4*)(xc1 + j * 32);
            t[j][1][1] = *(const f32x4*)(xc1 + j * 32 + 4);
        }
#pragma unroll
        for (int j = 0; j < 12; j++) {
            if (j < 10) {
                t[(j + 2) % 3][0][0] = *(const f32x4*)(xc0 + (j + 2) * 32);
                t[(j + 2) % 3][0][1] = *(const f32x4*)(xc0 + (j + 2) * 32 + 4);
                t[(j + 2) % 3][1][0] = *(const f32x4*)(xc1 + (j + 2) * 32);
                t[(j + 2) % 3][1][1] = *(const f32x4*)(xc1 + (j + 2) * 32 + 4);
            }
#pragma unroll
            for (int rt = 0; rt < 2; rt++) {
                short8 xs8;
#pragma unroll
                for (int e = 0; e < 4; e++) {
                    xs8[e]     = (short)f2bf(t[j % 3][rt][0][e]);
                    xs8[4 + e] = (short)f2bf(t[j % 3][rt][1][e]);
                }
                i32x4 v = __builtin_bit_cast(i32x4, xs8);
                sinki += v[0] + v[1] + v[2] + v[3];
            }
        }
        __syncthreads();
    }
    g_diag[b * 512 + tid] = (float)sinki + (sh[0] ? 0.f : 0.f);
}

// ---------------------------------------------------------------------------
// V4: SEGMENT-OPTIMAL x-stream + cvt, x nrep. Lane l <- bytes l*16 of a
// contiguous 1KB row-block (8 rows x 128B): every 64B segment touched once.
// Same bytes/cvt count as V2; half the L1 segment requests.
// ---------------------------------------------------------------------------
__global__ __launch_bounds__(512)
__attribute__((amdgpu_waves_per_eu(2, 2)))
void diag_v4(const float* __restrict__ x, int nrep) {
    extern __shared__ unsigned short sh[];     // unused; forces 1 block/CU
    const int tid = threadIdx.x, wave = tid >> 6, lane = tid & 63;
    const int b = blockIdx.x;
    // lane l -> row (l>>3) within 8-row group, cols (l&7)*4 .. +3
    const float* xw = x + (size_t)(b * 256 + wave * 32 + (lane >> 3)) * 384 + (lane & 7) * 4;

    int sinki = 0;
    for (int rep = 0; rep < nrep; rep++) {     // runtime trip
        f32x4 t[3][4];                          // ring: 4 loads per j (2rt x 2h)
#pragma unroll
        for (int j = 0; j < 2; j++)
#pragma unroll
            for (int g = 0; g < 4; g++)        // g = rt*2 + h -> row offset g*8
                t[j][g] = *(const f32x4*)(xw + (size_t)(g * 8) * 384 + j * 32);
#pragma unroll
        for (int j = 0; j < 12; j++) {
            if (j < 10) {
#pragma unroll
                for (int g = 0; g < 4; g++)
                    t[(j + 2) % 3][g] = *(const f32x4*)(xw + (size_t)(g * 8) * 384 + (j + 2) * 32);
            }
#pragma unroll
            for (int g = 0; g < 4; g++) {
#pragma unroll
                for (int e = 0; e < 4; e++)
                    sinki += (int)f2bf(t[j % 3][g][e]);
            }
        }
        __syncthreads();
    }
    g_diag[b * 512 + tid] = (float)sinki + (sh[0] ? 0.f : 0.f);
}

// ---------------------------------------------------------------------------
// REAL fused kernel: r17 VERBATIM (passed, 76.2 us, VGPR 92)
// ---------------------------------------------------------------------------
__global__ __launch_bounds__(512)
__attribute__((amdgpu_waves_per_eu(2, 2)))
void fused_kernel(
        const float* __restrict__ x, const unsigned short* __restrict__ Wt,
        const unsigned short* __restrict__ Rk, const float* __restrict__ relv,
        float* __restrict__ out) {
    extern __shared__ unsigned short sh[];
    unsigned short* ws  = sh;
    unsigned short* ksh = sh;
    unsigned short* vTs = sh + 18432;
    unsigned short* qs  = sh + 35328;

    const int tid  = threadIdx.x;
    const int wave = tid >> 6;
    const int lane = tid & 63;
    const int c    = lane & 15;
    const int quad = lane >> 4;
    const int b    = blockIdx.x;

    const f32x4 zero = {0.f, 0.f, 0.f, 0.f};

    const float* xc0 = x + (size_t)(b * 256 + wave * 32 + c) * 384 + quad * 8;
    const float* xc1 = xc0 + 16 * 384;

    f32x4 aq[2][4], ak[2][4], av[2][4];
#pragma unroll
    for (int rt = 0; rt < 2; rt++)
#pragma unroll
        for (int nt = 0; nt < 4; nt++) { aq[rt][nt] = zero; ak[rt][nt] = zero; av[rt][nt] = zero; }

    f32x4 t[3][2][2];
#pragma unroll
    for (int j = 0; j < 2; j++) {
        t[j][0][0] = *(const f32x4*)(xc0 + j * 32);
        t[j][0][1] = *(const f32x4*)(xc0 + j * 32 + 4);
        t[j][1][0] = *(const f32x4*)(xc1 + j * 32);
        t[j][1][1] = *(const f32x4*)(xc1 + j * 32 + 4);
    }

#pragma unroll
    for (int it = 0; it < 18; it++) {
        int P_ = it * 512 + tid;
        int r = P_ / 48, pc = P_ % 48;
        i32x4 d = *(const i32x4*)(Wt + r * 384 + pc * 8);
        *(i32x4*)(ws + r * 392 + pc * 8) = d;
    }
    __syncthreads();

#pragma unroll
    for (int j = 0; j < 12; j++) {
        if (j < 10) {
            t[(j + 2) % 3][0][0] = *(const f32x4*)(xc0 + (j + 2) * 32);
            t[(j + 2) % 3][0][1] = *(const f32x4*)(xc0 + (j + 2) * 32 + 4);
            t[(j + 2) % 3][1][0] = *(const f32x4*)(xc1 + (j + 2) * 32);
            t[(j + 2) % 3][1][1] = *(const f32x4*)(xc1 + (j + 2) * 32 + 4);
        }
        bf16x8 a[2];
#pragma unroll
        for (int rt = 0; rt < 2; rt++) {
            short8 xs8;
#pragma unroll
            for (int e = 0; e < 4; e++) {
                xs8[e]     = (short)f2bf(t[j % 3][rt][0][e]);
                xs8[4 + e] = (short)f2bf(t[j % 3][rt][1][e]);
            }
            a[rt] = __builtin_bit_cast(bf16x8, xs8);
        }
        const int col = j * 32 + quad * 8;

#pragma unroll
        for (int nt = 0; nt < 4; nt++) {
            bf16x8 bq = ld16(ws + (nt * 16 + c) * 392 + col);
            bf16x8 bk = ld16(ws + (64 + nt * 16 + c) * 392 + col);
            bf16x8 aw = ld16(ws + (128 + nt * 16 + c) * 392 + col);
            aq[0][nt] = MFMA16(a[0], bq, aq[0][nt]);
            aq[1][nt] = MFMA16(a[1], bq, aq[1][nt]);
            ak[0][nt] = MFMA16(a[0], bk, ak[0][nt]);
            ak[1][nt] = MFMA16(a[1], bk, ak[1][nt]);
            av[0][nt] = MFMA16(aw, a[0], av[0][nt]);
            av[1][nt] = MFMA16(aw, a[1], av[1][nt]);
        }
    }
    __syncthreads();

#pragma unroll
    for (int rt = 0; rt < 2; rt++)
#pragma unroll
        for (int nt = 0; nt < 4; nt++)
#pragma unroll
            for (int r = 0; r < 4; r++) {
                int row = wave * 32 + rt * 16 + quad * 4 + r;
                qs[row * 72 + nt * 16 + c]  = f2bf(aq[rt][nt][r]);
                ksh[row * 72 + nt * 16 + c] = f2bf(ak[rt][nt][r]);
                vTs[(nt * 16 + quad * 4 + r) * 264 + wave * 32 + rt * 16 + c]
                    = f2bf(av[rt][nt][r]);
            }
    __syncthreads();

    const int tA = wave, tB = 15 - wave;

    bf16x8 qA0 = ld16(qs + (tA * 16 + c) * 72 + quad * 8);
    bf16x8 qA1 = ld16(qs + (tA * 16 + c) * 72 + 32 + quad * 8);
    bf16x8 qB0 = ld16(qs + (tB * 16 + c) * 72 + quad * 8);
    bf16x8 qB1 = ld16(qs + (tB * 16 + c) * 72 + 32 + quad * 8);
    float rv[4][4];
#pragma unroll
    for (int j = 0; j < 4; j++)
#pragma unroll
        for (int nt = 0; nt < 4; nt++)
            rv[j][nt] = relv[j * 64 + nt * 16 + c];
    __syncthreads();

    unsigned short* Pw = sh + 35328 + wave * 4224;

#pragma unroll
    for (int it2 = 0; it2 < 2; it2++) {
        const int tt  = it2 ? tB : tA;
        const bf16x8 aq0 = it2 ? qB0 : qA0;
        const bf16x8 aq1 = it2 ? qB1 : qA1;
        const int nst = tt + 1;

        __asm__ __volatile__("s_waitcnt lgkmcnt(0)" ::: "memory");

        f32x4 e = zero;
        e = MFMA16(aq0, ld16(Rk + c * 64 + quad * 8), e);
        e = MFMA16(aq1, ld16(Rk + c * 64 + 32 + quad * 8), e);
        float ef[4][4];
#pragma unroll
        for (int r = 0; r < 4; r++)
#pragma unroll
            for (int n = 0; n < 4; n++)
                ef[r][n] = __shfl(e[r], (lane & 48) + n, 64);

        float l[4] = {0.f, 0.f, 0.f, 0.f};
#pragma unroll
        for (int st = 0; st < 16; st++) {
            if (st < nst) {
                const unsigned short* kp = ksh + (st * 16 + c) * 72 + quad * 8;
                f32x4 s = zero;
                s = MFMA16(aq0, ld16(kp), s);
                s = MFMA16(aq1, ld16(kp + 32), s);
#pragma unroll
                for (int r = 0; r < 4; r++) {
                    int tg = tt * 16 + quad * 4 + r;
                    int sg = st * 16 + c;
                    int d  = sg - tg;
                    float ee = (d <= -3) ? ef[r][0] : (d == -2) ? ef[r][1]
                             : (d == -1) ? ef[r][2] : ef[r][3];
                    float pv = (d > 0) ? 0.f : __expf(0.125f * (s[r] + ee));
                    l[r] += pv;
                    Pw[(quad * 4 + r) * 264 + sg] = f2bf(pv);
                }
            } else if (st == nst && (nst & 1)) {
#pragma unroll
                for (int r = 0; r < 4; r++)
                    Pw[(quad * 4 + r) * 264 + st * 16 + c] = 0;
            }
        }
#pragma unroll
        for (int r = 0; r < 4; r++)
#pragma unroll
            for (int ofs = 1; ofs < 16; ofs <<= 1)
                l[r] += __shfl_xor(l[r], ofs, 64);
        float rl[4];
#pragma unroll
        for (int r = 0; r < 4; r++) rl[r] = 1.0f / l[r];

        __asm__ __volatile__("s_waitcnt lgkmcnt(0)" ::: "memory");

        f32x4 o0[4], o1[4];
#pragma unroll
        for (int nt = 0; nt < 4; nt++) { o0[nt] = zero; o1[nt] = zero; }
        const int ksteps = (nst + 1) >> 1;
#pragma unroll
        for (int ks = 0; ks < 8; ks++) {
            if (ks < ksteps) {
                bf16x8 ap = ld16(Pw + c * 264 + ks * 32 + quad * 8);
#pragma unroll
                for (int nt = 0; nt < 4; nt++) {
                    bf16x8 bv = ld16(vTs + (nt * 16 + c) * 264 + ks * 32 + quad * 8);
                    if (ks & 1) o1[nt] = MFMA16(ap, bv, o1[nt]);
                    else        o0[nt] = MFMA16(ap, bv, o0[nt]);
                }
            }
        }

#pragma unroll
        for (int r = 0; r < 4; r++) {
            int tl = quad * 4 + r;
            int tg = tt * 16 + tl;
            float pa  = (tg >= 2) ? bf2f(Pw[tl * 264 + tg - 2]) * rl[r] : 0.f;
            float pb  = (tg >= 1) ? bf2f(Pw[tl * 264 + tg - 1]) * rl[r] : 0.f;
            float pcv = bf2f(Pw[tl * 264 + tg]) * rl[r];
#pragma unroll
            for (int nt = 0; nt < 4; nt++) {
                float r0 = rv[0][nt];
                float w2 = r0 + pa * (rv[1][nt] - r0) + pb * (rv[2][nt] - r0)
                              + pcv * (rv[3][nt] - r0);
                out[(size_t)(b * 256 + tg) * 64 + nt * 16 + c]
                    = (o0[nt][r] + o1[nt][r]) * rl[r] + w2;
            }
        }
    }
}

// ---------------------------------------------------------------------------
extern "C" void kernel_launch(void* const* d_in, const int* in_sizes, int n_in,
                              void* d_out, int out_size, void* d_ws, size_t ws_size,
                              hipStream_t stream) {
    const float* x    = (const float*)d_in[0];
    const float* Wq   = (const float*)d_in[1];
    const float* Wk   = (const float*)d_in[2];
    const float* Wv   = (const float*)d_in[3];
    const float* relk = (const float*)d_in[4];
    const float* relv = (const float*)d_in[5];
    float* out = (float*)d_out;

    char* ws = (char*)d_ws;
    unsigned short* Wt = (unsigned short*)(ws);              // 147456 B
    unsigned short* Rk = (unsigned short*)(ws + 147456);     // 2048 B

    (void)hipFuncSetAttribute((const void*)fused_kernel,
                              hipFuncAttributeMaxDynamicSharedMemorySize, 150528);
    (void)hipFuncSetAttribute((const void*)diag_v0,
                              hipFuncAttributeMaxDynamicSharedMemorySize, 150528);
    (void)hipFuncSetAttribute((const void*)diag_v1,
                              hipFuncAttributeMaxDynamicSharedMemorySize, 150528);
    (void)hipFuncSetAttribute((const void*)diag_v2,
                              hipFuncAttributeMaxDynamicSharedMemorySize, 150528);
    (void)hipFuncSetAttribute((const void*)diag_v4,
                              hipFuncAttributeMaxDynamicSharedMemorySize, 150528);

    prep_wt<<<292, 256, 0, stream>>>(Wq, Wk, Wv, relk, Wt, Rk);
    diag_v0<<<256, 512, 150528, stream>>>(x, Wt, 3);
    diag_v1<<<256, 512, 150528, stream>>>(Wt, relv, 4);
    diag_v2<<<256, 512, 150528, stream>>>(x, 5);
    diag_v4<<<256, 512, 150528, stream>>>(x, 5);
    fused_kernel<<<256, 512, 150528, stream>>>(x, Wt, Rk, relv, out);
}

// Round 12
// 195.495 us; speedup vs baseline: 1.7658x; 1.7658x over previous
//
#include <hip/hip_runtime.h>
#include <hip/hip_bf16.h>

// Problem: B=256, T=256, C=384, H=64, MAX_REL=3 (causal -> rel idx 0..3 only)
// Round 19: from r18's ablation -- phase-1 composite = 40 us warm / ~120 cold
// while its parts (x-stream <=12, core <=14) are cheap: the cost is exposed
// latency in the per-j {load->vmcnt->cvt->ds_read->MFMA} chain at 2 waves/SIMD
// with only a depth-2 ring (~400cy cover vs ~900cy HBM; harness fill evicts
// L3 every iteration so x is always cold). Two changes, rest r17 verbatim:
//   (a) prefetch ring depth 4 (t[5][2][2], 16 loads/wave in flight ~ 4 MFMA
//       iterations + W-stage of cover >= 1600cy)
//   (b) v_cvt_pk_bf16_f32 (T12, gfx950-verified) for A-frag cvt: 8 insts/j
//       instead of 48 hand-rolled RNE ops on the load->MFMA critical path.

typedef __attribute__((ext_vector_type(8))) __bf16 bf16x8;
typedef __attribute__((ext_vector_type(8))) short short8;
typedef __attribute__((ext_vector_type(4))) float f32x4;
typedef __attribute__((ext_vector_type(4))) int   i32x4;

#define MFMA16(A, B, C) __builtin_amdgcn_mfma_f32_16x16x32_bf16((A), (B), (C), 0, 0, 0)

__device__ __forceinline__ unsigned short f2bf(float f) {
    unsigned int u = __builtin_bit_cast(unsigned int, f);
    u = (u + 0x7FFFu + ((u >> 16) & 1u)) >> 16;   // RNE
    return (unsigned short)u;
}
__device__ __forceinline__ float bf2f(unsigned short s) {
    unsigned int u = ((unsigned int)s) << 16;
    return __builtin_bit_cast(float, u);
}
__device__ __forceinline__ bf16x8 ld16(const unsigned short* p) {
    return __builtin_bit_cast(bf16x8, *(const i32x4*)p);
}
// 8x f32 -> bf16x8 via v_cvt_pk_bf16_f32 (RNE, 2 elems/inst; gfx950 has no builtin)
__device__ __forceinline__ bf16x8 cvt8(f32x4 lo, f32x4 hi) {
    i32x4 d;
    asm("v_cvt_pk_bf16_f32 %0, %1, %2" : "=v"(d[0]) : "v"(lo[0]), "v"(lo[1]));
    asm("v_cvt_pk_bf16_f32 %0, %1, %2" : "=v"(d[1]) : "v"(lo[2]), "v"(lo[3]));
    asm("v_cvt_pk_bf16_f32 %0, %1, %2" : "=v"(d[2]) : "v"(hi[0]), "v"(hi[1]));
    asm("v_cvt_pk_bf16_f32 %0, %1, %2" : "=v"(d[3]) : "v"(hi[2]), "v"(hi[3]));
    return __builtin_bit_cast(bf16x8, d);
}

// ---------------------------------------------------------------------------
// Kernel 0: Wt[3][64][384] bf16 (W^T) + Rk[16][64] bf16 (rel_k rows 0..3, rest 0)
// ---------------------------------------------------------------------------
__global__ void prep_wt(const float* __restrict__ Wq, const float* __restrict__ Wk,
                        const float* __restrict__ Wv, const float* __restrict__ relk,
                        unsigned short* __restrict__ Wt, unsigned short* __restrict__ Rk) {
    int i = blockIdx.x * 256 + threadIdx.x;
    if (i < 3 * 64 * 384) {
        int kk = i % 384;
        int h  = (i / 384) & 63;
        int w  = i / (384 * 64);
        const float* W = (w == 0) ? Wq : ((w == 1) ? Wk : Wv);
        Wt[i] = f2bf(W[kk * 64 + h]);
    } else if (i < 3 * 64 * 384 + 1024) {
        int j = i - 3 * 64 * 384;
        int n = j >> 6, h = j & 63;
        Rk[j] = (n < 4) ? f2bf(relk[n * 64 + h]) : (unsigned short)0;
    }
}

// ---------------------------------------------------------------------------
// Fused QKV + attention. One block per batch, 512 threads (8 waves),
// 2 waves/SIMD -> 256-VGPR budget (honored: r17 measured alloc 92 for 92
// demand). LDS (u16 offsets; request 150528 B):
//   phase 1: ws [192][392] @ 0   150528 B (whole W^T, staged once)
//   phase 2 overlays ws:
//     ksh [256][72] @ 0; vTs [64][264] @ 18432; qs [256][72] @ 35328
//     P(wave w) = 35328 + w*4224, [16][264]
// ---------------------------------------------------------------------------
__global__ __launch_bounds__(512)
__attribute__((amdgpu_waves_per_eu(2, 2)))
void fused_kernel(
        const float* __restrict__ x, const unsigned short* __restrict__ Wt,
        const unsigned short* __restrict__ Rk, const float* __restrict__ relv,
        float* __restrict__ out) {
    extern __shared__ unsigned short sh[];
    unsigned short* ws  = sh;                  // phase 1
    unsigned short* ksh = sh;                  // phase 2
    unsigned short* vTs = sh + 18432;
    unsigned short* qs  = sh + 35328;

    const int tid  = threadIdx.x;
    const int wave = tid >> 6;
    const int lane = tid & 63;
    const int c    = lane & 15;
    const int quad = lane >> 4;
    const int b    = blockIdx.x;

    const f32x4 zero = {0.f, 0.f, 0.f, 0.f};

    // =================== phase 1: QKV GEMM (depth-4 x ring) =================
    // wave owns rows wave*32 + rt*16 + c ; lane col j*32 + quad*8
    const float* xc0 = x + (size_t)(b * 256 + wave * 32 + c) * 384 + quad * 8;
    const float* xc1 = xc0 + 16 * 384;

    f32x4 aq[2][4], ak[2][4], av[2][4];
#pragma unroll
    for (int rt = 0; rt < 2; rt++)
#pragma unroll
        for (int nt = 0; nt < 4; nt++) { aq[rt][nt] = zero; ak[rt][nt] = zero; av[rt][nt] = zero; }

    // depth-4 ring: issue j=0..3 (16 loads/wave) BEFORE W staging
    f32x4 t[5][2][2];
#pragma unroll
    for (int j = 0; j < 4; j++) {
        t[j][0][0] = *(const f32x4*)(xc0 + j * 32);
        t[j][0][1] = *(const f32x4*)(xc0 + j * 32 + 4);
        t[j][1][0] = *(const f32x4*)(xc1 + j * 32);
        t[j][1][1] = *(const f32x4*)(xc1 + j * 32 + 4);
    }

    // stage ALL of W once: 9216 b128 pieces, 18/thread (L2-hot)
#pragma unroll
    for (int it = 0; it < 18; it++) {
        int P_ = it * 512 + tid;
        int r = P_ / 48, pc = P_ % 48;
        i32x4 d = *(const i32x4*)(Wt + r * 384 + pc * 8);
        *(i32x4*)(ws + r * 392 + pc * 8) = d;
    }
    __syncthreads();                           // W resident (x loads in flight)

#pragma unroll
    for (int j = 0; j < 12; j++) {
        // prefetch j+4 into the slot consumed 1 iter ago (4 iters in flight)
        if (j < 8) {
            const int s = (j + 4) % 5;
            t[s][0][0] = *(const f32x4*)(xc0 + (j + 4) * 32);
            t[s][0][1] = *(const f32x4*)(xc0 + (j + 4) * 32 + 4);
            t[s][1][0] = *(const f32x4*)(xc1 + (j + 4) * 32);
            t[s][1][1] = *(const f32x4*)(xc1 + (j + 4) * 32 + 4);
        }
        // convert both row-tiles via v_cvt_pk_bf16_f32 (8 insts total)
        bf16x8 a[2];
        a[0] = cvt8(t[j % 5][0][0], t[j % 5][0][1]);
        a[1] = cvt8(t[j % 5][1][0], t[j % 5][1][1]);
        const int col = j * 32 + quad * 8;

        // 3 B-frag LDS loads feed 6 MFMAs (row-tiles share W fragments)
#pragma unroll
        for (int nt = 0; nt < 4; nt++) {
            bf16x8 bq = ld16(ws + (nt * 16 + c) * 392 + col);
            bf16x8 bk = ld16(ws + (64 + nt * 16 + c) * 392 + col);
            bf16x8 aw = ld16(ws + (128 + nt * 16 + c) * 392 + col);
            aq[0][nt] = MFMA16(a[0], bq, aq[0][nt]);   // D[t][h]
            aq[1][nt] = MFMA16(a[1], bq, aq[1][nt]);
            ak[0][nt] = MFMA16(a[0], bk, ak[0][nt]);
            ak[1][nt] = MFMA16(a[1], bk, ak[1][nt]);
            av[0][nt] = MFMA16(aw, a[0], av[0][nt]);   // D[h][t]
            av[1][nt] = MFMA16(aw, a[1], av[1][nt]);
        }
    }
    __syncthreads();                           // all W reads done -> may overwrite

    // epilogue into LDS (C/D layout: col=lane&15, row=quad*4+reg)
#pragma unroll
    for (int rt = 0; rt < 2; rt++)
#pragma unroll
        for (int nt = 0; nt < 4; nt++)
#pragma unroll
            for (int r = 0; r < 4; r++) {
                int row = wave * 32 + rt * 16 + quad * 4 + r;
                qs[row * 72 + nt * 16 + c]  = f2bf(aq[rt][nt][r]);
                ksh[row * 72 + nt * 16 + c] = f2bf(ak[rt][nt][r]);
                vTs[(nt * 16 + quad * 4 + r) * 264 + wave * 32 + rt * 16 + c]
                    = f2bf(av[rt][nt][r]);
            }
    __syncthreads();                           // q/k/vT visible to all waves

    // =================== phase 2: attention, BARRIER-FREE ===================
    // wave w owns q-tiles {w, 15-w} entirely; Pw is wave-private.
    const int tA = wave, tB = 15 - wave;

    bf16x8 qA0 = ld16(qs + (tA * 16 + c) * 72 + quad * 8);
    bf16x8 qA1 = ld16(qs + (tA * 16 + c) * 72 + 32 + quad * 8);
    bf16x8 qB0 = ld16(qs + (tB * 16 + c) * 72 + quad * 8);
    bf16x8 qB1 = ld16(qs + (tB * 16 + c) * 72 + 32 + quad * 8);
    float rv[4][4];
#pragma unroll
    for (int j = 0; j < 4; j++)
#pragma unroll
        for (int nt = 0; nt < 4; nt++)
            rv[j][nt] = relv[j * 64 + nt * 16 + c];
    __syncthreads();                           // qs reads done -> P may overwrite

    unsigned short* Pw = sh + 35328 + wave * 4224;   // per-WAVE [16][264]

#pragma unroll
    for (int it2 = 0; it2 < 2; it2++) {
        const int tt  = it2 ? tB : tA;
        const bf16x8 aq0 = it2 ? qB0 : qA0;
        const bf16x8 aq1 = it2 ? qB1 : qA1;
        const int nst = tt + 1;

        // previous tile's P reads retire before overwriting (wave-local order)
        __asm__ __volatile__("s_waitcnt lgkmcnt(0)" ::: "memory");

        // E via MFMA vs Rk: D[m=quad*4+r][n=c] = q_{t0+m} . relk_n  (n<4 valid)
        f32x4 e = zero;
        e = MFMA16(aq0, ld16(Rk + c * 64 + quad * 8), e);
        e = MFMA16(aq1, ld16(Rk + c * 64 + 32 + quad * 8), e);
        float ef[4][4];
#pragma unroll
        for (int r = 0; r < 4; r++)
#pragma unroll
            for (int n = 0; n < 4; n++)
                ef[r][n] = __shfl(e[r], (lane & 48) + n, 64);

        // score tiles -> exp -> P^ in LDS; accumulate row sums
        float l[4] = {0.f, 0.f, 0.f, 0.f};
#pragma unroll
        for (int st = 0; st < 16; st++) {
            if (st < nst) {
                const unsigned short* kp = ksh + (st * 16 + c) * 72 + quad * 8;
                f32x4 s = zero;
                s = MFMA16(aq0, ld16(kp), s);
                s = MFMA16(aq1, ld16(kp + 32), s);
#pragma unroll
                for (int r = 0; r < 4; r++) {
                    int tg = tt * 16 + quad * 4 + r;
                    int sg = st * 16 + c;
                    int d  = sg - tg;
                    float ee = (d <= -3) ? ef[r][0] : (d == -2) ? ef[r][1]
                             : (d == -1) ? ef[r][2] : ef[r][3];
                    float pv = (d > 0) ? 0.f : __expf(0.125f * (s[r] + ee));
                    l[r] += pv;
                    Pw[(quad * 4 + r) * 264 + sg] = f2bf(pv);
                }
            } else if (st == nst && (nst & 1)) {
                // zero-pad the half-open MFMA k-tile when nst is odd
#pragma unroll
                for (int r = 0; r < 4; r++)
                    Pw[(quad * 4 + r) * 264 + st * 16 + c] = 0;
            }
        }
        // row-sum over the 16 c-lanes (same quad)
#pragma unroll
        for (int r = 0; r < 4; r++)
#pragma unroll
            for (int ofs = 1; ofs < 16; ofs <<= 1)
                l[r] += __shfl_xor(l[r], ofs, 64);
        float rl[4];
#pragma unroll
        for (int r = 0; r < 4; r++) rl[r] = 1.0f / l[r];

        __asm__ __volatile__("s_waitcnt lgkmcnt(0)" ::: "memory");  // P^ visible

        // O = P^ @ V; accumulator chains split by ks parity
        f32x4 o0[4], o1[4];
#pragma unroll
        for (int nt = 0; nt < 4; nt++) { o0[nt] = zero; o1[nt] = zero; }
        const int ksteps = (nst + 1) >> 1;
#pragma unroll
        for (int ks = 0; ks < 8; ks++) {
            if (ks < ksteps) {
                bf16x8 ap = ld16(Pw + c * 264 + ks * 32 + quad * 8);
#pragma unroll
                for (int nt = 0; nt < 4; nt++) {
                    bf16x8 bv = ld16(vTs + (nt * 16 + c) * 264 + ks * 32 + quad * 8);
                    if (ks & 1) o1[nt] = MFMA16(ap, bv, o1[nt]);
                    else        o0[nt] = MFMA16(ap, bv, o0[nt]);
                }
            }
        }

        // epilogue: normalize + w2 band-probability identity + store
#pragma unroll
        for (int r = 0; r < 4; r++) {
            int tl = quad * 4 + r;
            int tg = tt * 16 + tl;
            float pa  = (tg >= 2) ? bf2f(Pw[tl * 264 + tg - 2]) * rl[r] : 0.f;
            float pb  = (tg >= 1) ? bf2f(Pw[tl * 264 + tg - 1]) * rl[r] : 0.f;
            float pcv = bf2f(Pw[tl * 264 + tg]) * rl[r];
#pragma unroll
            for (int nt = 0; nt < 4; nt++) {
                float r0 = rv[0][nt];
                float w2 = r0 + pa * (rv[1][nt] - r0) + pb * (rv[2][nt] - r0)
                              + pcv * (rv[3][nt] - r0);
                out[(size_t)(b * 256 + tg) * 64 + nt * 16 + c]
                    = (o0[nt][r] + o1[nt][r]) * rl[r] + w2;
            }
        }
    }
}

// ---------------------------------------------------------------------------
extern "C" void kernel_launch(void* const* d_in, const int* in_sizes, int n_in,
                              void* d_out, int out_size, void* d_ws, size_t ws_size,
                              hipStream_t stream) {
    const float* x    = (const float*)d_in[0];
    const float* Wq   = (const float*)d_in[1];
    const float* Wk   = (const float*)d_in[2];
    const float* Wv   = (const float*)d_in[3];
    const float* relk = (const float*)d_in[4];
    const float* relv = (const float*)d_in[5];
    float* out = (float*)d_out;

    char* ws = (char*)d_ws;
    unsigned short* Wt = (unsigned short*)(ws);              // 147456 B
    unsigned short* Rk = (unsigned short*)(ws + 147456);     // 2048 B

    (void)hipFuncSetAttribute((const void*)fused_kernel,
                              hipFuncAttributeMaxDynamicSharedMemorySize, 150528);

    prep_wt<<<292, 256, 0, stream>>>(Wq, Wk, Wv, relk, Wt, Rk);
    fused_kernel<<<256, 512, 150528, stream>>>(x, Wt, Rk, relv, out);
}